// Round 13
// baseline (2958.964 us; speedup 1.0000x reference)
//
#include <hip/hip_runtime.h>

// ---------------- problem constants ----------------
#define T_STEPS 512
#define BATCH_N 256
#define IDIM    128
#define NDIM    1024
#define ODIM    10

// 128 WGs = 16 col-slices(64 cols) x 8 pairs; 4 waves. Each WG serves TWO
// independent batch-groups (gA=pair, gB=pair+8) sharing W/i2h registers.
// Corrected k=2 schedule (vs R12): no mid-pipeline vmcnt(0) drains, raw
// s_barrier (lgkm-only), per-stream LDS buffers, spin+issue for the OTHER
// stream right after bar1 (its flags are ~1 service old -> near-instant),
// per-wave flags after per-wave folded drain (no bar3).
#define THREADS 256
#define GAIN 0.03125f

// ---------------- workspace layout (bytes) ----------------
#define YBUF_OFF    (33554432ull)                 // bf16 y [2][16][16][1024]
#define YBUF_HALF   (524288ull)
#define YHALF_EL    (262144u)
#define FLG_OFF     (YBUF_OFF + 2*YBUF_HALF)
#define FLG_BYTES   (4096ull)                     // u32 [16 groups][64 waves]
#define XT_OFF      (FLG_OFF + FLG_BYTES)
#define XT_BYTES    (1048576ull)
#define WS_NEED     (XT_OFF + XT_BYTES)

typedef short    s16x8 __attribute__((ext_vector_type(8)));
typedef float    f32x4 __attribute__((ext_vector_type(4)));
typedef unsigned u32x4 __attribute__((ext_vector_type(4)));

__device__ __forceinline__ unsigned short f2bf(float f) {
  unsigned u = __builtin_bit_cast(unsigned, f);
  u += 0x7fffu + ((u >> 16) & 1u);               // RTNE
  return (unsigned short)(u >> 16);
}

// ---------------- batch fp32 -> bf16 prepass ----------------
__global__ void horn_convert(const float* __restrict__ src, unsigned short* __restrict__ dst) {
  size_t gid = (size_t)blockIdx.x * 256 + threadIdx.x;
  const f32x4* s4 = reinterpret_cast<const f32x4*>(src) + gid * 2;
  f32x4 a = s4[0], b = s4[1];
  u32x4 o;
  o[0] = (unsigned)f2bf(a[0]) | ((unsigned)f2bf(a[1]) << 16);
  o[1] = (unsigned)f2bf(a[2]) | ((unsigned)f2bf(a[3]) << 16);
  o[2] = (unsigned)f2bf(b[0]) | ((unsigned)f2bf(b[1]) << 16);
  o[3] = (unsigned)f2bf(b[2]) | ((unsigned)f2bf(b[3]) << 16);
  reinterpret_cast<u32x4*>(dst)[gid] = o;
}

// ---------------- persistent recurrent kernel ----------------
// LDS (dynamic 80KB): yldsA 32KB | yldsB 32KB | red[4][4][64] f32x4 16KB
__launch_bounds__(THREADS, 1)
__global__ void horn_persistent(const unsigned short* __restrict__ batchbf,
                                const float* __restrict__ i2h_w,
                                const float* __restrict__ i2h_b,
                                const float* __restrict__ h2h_w,
                                const float* __restrict__ h2h_b,
                                unsigned short* ybuf,     // bf16 [2][16][16][1024]
                                unsigned int*  flags,     // u32 [16][64]
                                float* xT)                // [256][1024] fp32
{
  extern __shared__ char smem[];
  char*  yldsA = smem;
  char*  yldsB = smem + 32768;
  f32x4* red   = (f32x4*)(smem + 65536);           // [wv][ct][lane]

  const int tid  = threadIdx.x;
  const int lane = tid & 63;
  const int wv   = tid >> 6;          // wave 0..3: K-quarter wv, owned ct = wv
  const int pr   = blockIdx.x & 7;    // pair
  const int s    = blockIdx.x >> 3;   // col-slice 0..15 (64 cols)
  const int l15  = lane & 15;
  const int kb   = lane >> 4;
  const int jc   = s * 64 + wv * 16 + l15;         // owned output column
  const int gA   = pr, gB = pr + 8;

  // ---- W fragments (shared by both streams): 4 ct x 8 kc, xGAIN ----
  s16x8 wfrag[4][8];
  #pragma unroll
  for (int ct = 0; ct < 4; ++ct) {
    #pragma unroll
    for (int kc = 0; kc < 8; ++kc) {
      const float* gp = h2h_w + (size_t)(s * 64 + ct * 16 + l15) * NDIM
                        + wv * 256 + kc * 32 + kb * 8;
      f32x4 a = *reinterpret_cast<const f32x4*>(gp);
      f32x4 b = *reinterpret_cast<const f32x4*>(gp + 4);
      s16x8 v;
      v[0] = (short)f2bf(a[0]*GAIN); v[1] = (short)f2bf(a[1]*GAIN);
      v[2] = (short)f2bf(a[2]*GAIN); v[3] = (short)f2bf(a[3]*GAIN);
      v[4] = (short)f2bf(b[0]*GAIN); v[5] = (short)f2bf(b[1]*GAIN);
      v[6] = (short)f2bf(b[2]*GAIN); v[7] = (short)f2bf(b[3]*GAIN);
      wfrag[ct][kc] = v;
    }
  }
  s16x8 i2hf[4];
  #pragma unroll
  for (int kc = 0; kc < 4; ++kc) {
    const float* gp = i2h_w + (size_t)jc * IDIM + kc * 32 + kb * 8;
    s16x8 v;
    #pragma unroll
    for (int e = 0; e < 8; ++e) v[e] = (short)f2bf(gp[e]);
    i2hf[kc] = v;
  }
  const float bias = i2h_b[jc] + GAIN * h2h_b[jc];

  // ---- per-stream pointers ----
  const char* gbA = (const char*)ybuf + (size_t)gA * 32768 + (size_t)tid * 16;
  const char* gbB = (const char*)ybuf + (size_t)gB * 32768 + (size_t)tid * 16;
  unsigned short* pubA = ybuf + (size_t)(gA * 16 + kb * 4) * 1024 + jc;
  unsigned short* pubB = ybuf + (size_t)(gB * 16 + kb * 4) * 1024 + jc;
  const unsigned* fpA = flags + gA * 64 + lane;
  const unsigned* fpB = flags + gB * 64 + lane;
  unsigned* fsA = flags + gA * 64 + s * 4 + wv;
  unsigned* fsB = flags + gB * 64 + s * 4 + wv;

  float xsA[4] = {0,0,0,0}, ysA[4] = {0,0,0,0};
  float xsB[4] = {0,0,0,0}, ysB[4] = {0,0,0,0};
  s16x8 bfrA[4], bfrB[4];
  u32x4 vy0, vy1, vy2, vy3, vy4, vy5, vy6, vy7;

  #define BARRIER() do { \
    asm volatile("s_waitcnt lgkmcnt(0)" ::: "memory"); \
    __builtin_amdgcn_sched_barrier(0); \
    __builtin_amdgcn_s_barrier(); \
    __builtin_amdgcn_sched_barrier(0); } while (0)

  #define SPIN(fp, tgt) { while (true) { unsigned fv_; \
    asm volatile("global_load_dword %0, %1, off sc0 sc1\n\ts_waitcnt vmcnt(0)" \
                 : "=v"(fv_) : "v"(fp) : "memory"); \
    if (__all((int)fv_ >= (tgt))) break; \
    __builtin_amdgcn_s_sleep(1); } }

  #define ISSUE8(ya) asm volatile( \
    "global_load_dwordx4 %0, %8, off sc0 sc1\n\t" \
    "global_load_dwordx4 %1, %9, off sc0 sc1\n\t" \
    "global_load_dwordx4 %2, %10, off sc0 sc1\n\t" \
    "global_load_dwordx4 %3, %11, off sc0 sc1\n\t" \
    "global_load_dwordx4 %4, %12, off sc0 sc1\n\t" \
    "global_load_dwordx4 %5, %13, off sc0 sc1\n\t" \
    "global_load_dwordx4 %6, %14, off sc0 sc1\n\t" \
    "global_load_dwordx4 %7, %15, off sc0 sc1" \
    : "=&v"(vy0), "=&v"(vy1), "=&v"(vy2), "=&v"(vy3), \
      "=&v"(vy4), "=&v"(vy5), "=&v"(vy6), "=&v"(vy7) \
    : "v"(ya), "v"((ya)+4096), "v"((ya)+8192), "v"((ya)+12288), \
      "v"((ya)+16384), "v"((ya)+20480), "v"((ya)+24576), "v"((ya)+28672) \
    : "memory")

  #define LOADBATCH(bfr, g, t) { \
    const unsigned short* bp_ = batchbf + ((size_t)(t) * BATCH_N + (g) * 16 + l15) * IDIM + kb * 8; \
    _Pragma("unroll") \
    for (int kc = 0; kc < 4; ++kc) bfr[kc] = *reinterpret_cast<const s16x8*>(bp_ + kc * 32); }

  #define STG8(YL) { \
    _Pragma("unroll") \
    for (int r_ = 0; r_ < 8; ++r_) { \
      u32x4 vr_ = (r_==0)?vy0:(r_==1)?vy1:(r_==2)?vy2:(r_==3)?vy3:(r_==4)?vy4:(r_==5)?vy5:(r_==6)?vy6:vy7; \
      int B_ = r_ * 4096 + tid * 16; int row_ = B_ >> 11; \
      *reinterpret_cast<u32x4*>((YL) + (B_ ^ ((row_ & 7) << 4))) = vr_; } }

  #define UPD4(xs, ys, z) \
    unsigned yw0, yw1, yw2, yw3; { float z_, e_, th_, yn_; \
    z_ = z[0]; e_ = __expf(z_ + z_); th_ = fmaf(-2.0f, __builtin_amdgcn_rcpf(e_ + 1.0f), 1.0f); \
    yn_ = ys[0] + 0.1f*(th_ - xs[0] - 0.2f*ys[0]); xs[0] += 0.1f*yn_; ys[0] = yn_; yw0 = f2bf(yn_); \
    z_ = z[1]; e_ = __expf(z_ + z_); th_ = fmaf(-2.0f, __builtin_amdgcn_rcpf(e_ + 1.0f), 1.0f); \
    yn_ = ys[1] + 0.1f*(th_ - xs[1] - 0.2f*ys[1]); xs[1] += 0.1f*yn_; ys[1] = yn_; yw1 = f2bf(yn_); \
    z_ = z[2]; e_ = __expf(z_ + z_); th_ = fmaf(-2.0f, __builtin_amdgcn_rcpf(e_ + 1.0f), 1.0f); \
    yn_ = ys[2] + 0.1f*(th_ - xs[2] - 0.2f*ys[2]); xs[2] += 0.1f*yn_; ys[2] = yn_; yw2 = f2bf(yn_); \
    z_ = z[3]; e_ = __expf(z_ + z_); th_ = fmaf(-2.0f, __builtin_amdgcn_rcpf(e_ + 1.0f), 1.0f); \
    yn_ = ys[3] + 0.1f*(th_ - xs[3] - 0.2f*ys[3]); xs[3] += 0.1f*yn_; ys[3] = yn_; yw3 = f2bf(yn_); }

  #define PUBLISH(pub, PN) { \
    unsigned short* b0_ = (pub) + (size_t)(PN) * YHALF_EL; \
    unsigned short* b1_ = b0_ + 2 * NDIM; \
    asm volatile( \
      "global_store_short %4, %0, off offset:0    sc0 sc1\n\t" \
      "global_store_short %4, %1, off offset:2048 sc0 sc1\n\t" \
      "global_store_short %5, %2, off offset:0    sc0 sc1\n\t" \
      "global_store_short %5, %3, off offset:2048 sc0 sc1" \
      :: "v"(yw0), "v"(yw1), "v"(yw2), "v"(yw3), "v"(b0_), "v"(b1_) : "memory"); }

  #define SETFLAG(fs, val) { unsigned nv_ = (unsigned)(val); \
    asm volatile("global_store_dword %0, %1, off sc0 sc1" :: "v"(fs), "v"(nv_) : "memory"); }

  // one service: consume own bundle, stage, bar1, [spin other + issue other],
  // u+rec, red, bar2, reduce, update, publish, drain, per-wave flag.
  #define SERVICE(YL, bfrX, xsX, ysX, pubX, fsX, fpO, gbO, gO, bfrO, SPT, IST, DOISS, PN, FLV) \
  { \
    asm volatile("s_waitcnt vmcnt(0)" ::: "memory"); \
    __builtin_amdgcn_sched_barrier(0); \
    STG8(YL) \
    BARRIER();                                   /* bar1: tile staged */ \
    if (DOISS) { \
      SPIN(fpO, SPT) \
      const char* ya_ = (gbO) + (size_t)((IST) & 1) * YBUF_HALF; \
      ISSUE8(ya_); \
      LOADBATCH(bfrO, gO, IST) \
    } \
    f32x4 uacc = {bias, bias, bias, bias}; \
    _Pragma("unroll") \
    for (int kc = 0; kc < 4; ++kc) \
      uacc = __builtin_amdgcn_mfma_f32_16x16x32_bf16(bfrX[kc], i2hf[kc], uacc, 0, 0, 0); \
    f32x4 c0 = {0,0,0,0}, c1 = {0,0,0,0}, c2 = {0,0,0,0}, c3 = {0,0,0,0}; \
    _Pragma("unroll") \
    for (int kc = 0; kc < 8; ++kc) { \
      int boff = (l15 * 2048 + wv * 512 + kc * 64 + kb * 16) ^ ((l15 & 7) << 4); \
      s16x8 a_ = *reinterpret_cast<const s16x8*>((YL) + boff); \
      c0 = __builtin_amdgcn_mfma_f32_16x16x32_bf16(a_, wfrag[0][kc], c0, 0, 0, 0); \
      c1 = __builtin_amdgcn_mfma_f32_16x16x32_bf16(a_, wfrag[1][kc], c1, 0, 0, 0); \
      c2 = __builtin_amdgcn_mfma_f32_16x16x32_bf16(a_, wfrag[2][kc], c2, 0, 0, 0); \
      c3 = __builtin_amdgcn_mfma_f32_16x16x32_bf16(a_, wfrag[3][kc], c3, 0, 0, 0); \
    } \
    red[(wv * 4 + 0) * 64 + lane] = c0; red[(wv * 4 + 1) * 64 + lane] = c1; \
    red[(wv * 4 + 2) * 64 + lane] = c2; red[(wv * 4 + 3) * 64 + lane] = c3; \
    BARRIER();                                   /* bar2: partials ready */ \
    f32x4 z = uacc; \
    z += red[(0 * 4 + wv) * 64 + lane]; z += red[(1 * 4 + wv) * 64 + lane]; \
    z += red[(2 * 4 + wv) * 64 + lane]; z += red[(3 * 4 + wv) * 64 + lane]; \
    UPD4(xsX, ysX, z) \
    PUBLISH(pubX, PN) \
    asm volatile("s_waitcnt vmcnt(0)" ::: "memory"); \
    SETFLAG(fsX, FLV) \
  }

  // ---- prologue: t=0 is u-only (y_0 = 0) for both streams ----
  LOADBATCH(bfrA, gA, 0)
  LOADBATCH(bfrB, gB, 0)
  {
    f32x4 uacc = {bias, bias, bias, bias};
    #pragma unroll
    for (int kc = 0; kc < 4; ++kc)
      uacc = __builtin_amdgcn_mfma_f32_16x16x32_bf16(bfrA[kc], i2hf[kc], uacc, 0, 0, 0);
    UPD4(xsA, ysA, uacc)
    PUBLISH(pubA, 1)
  }
  {
    f32x4 uacc = {bias, bias, bias, bias};
    #pragma unroll
    for (int kc = 0; kc < 4; ++kc)
      uacc = __builtin_amdgcn_mfma_f32_16x16x32_bf16(bfrB[kc], i2hf[kc], uacc, 0, 0, 0);
    UPD4(xsB, ysB, uacc)
    PUBLISH(pubB, 1)
  }
  asm volatile("s_waitcnt vmcnt(0)" ::: "memory");
  SETFLAG(fsA, 1)
  SETFLAG(fsB, 1)
  // issue A-gather(1) once its producers are flagged
  SPIN(fpA, 1)
  { const char* ya_ = gbA + YBUF_HALF; ISSUE8(ya_); }
  LOADBATCH(bfrA, gA, 1)

  #pragma unroll 1
  for (int t = 1; t < T_STEPS; ++t) {
    const int pn = (t + 1) & 1;
    // service A(t): consumes A-bundle; spins B>=t, issues B(t)
    SERVICE(yldsA, bfrA, xsA, ysA, pubA, fsA, fpB, gbB, gB, bfrB,
            t, t, 1, pn, t + 1)
    // service B(t): consumes B-bundle; spins A>=t+1, issues A(t+1)
    SERVICE(yldsB, bfrB, xsB, ysB, pubB, fsB, fpA, gbA, gA, bfrA,
            t + 1, t + 1, (t < T_STEPS - 1), pn, t + 1)
  }
  #undef SERVICE

  // ---- write x_T for both streams ----
  #pragma unroll
  for (int q = 0; q < 4; ++q) {
    int rowA = gA * 16 + kb * 4 + q;
    int rowB = gB * 16 + kb * 4 + q;
    xT[(size_t)rowA * NDIM + jc] = xsA[q];
    xT[(size_t)rowB * NDIM + jc] = xsB[q];
  }
}

// ---------------- final readout: out = x_T @ h2o^T + b ----------------
__global__ void horn_out(const float* __restrict__ xT, const float* __restrict__ h2o_w,
                         const float* __restrict__ h2o_b, float* __restrict__ out) {
  int b = blockIdx.x;
  int lane = threadIdx.x;                  // 64 threads
  float p[ODIM];
  #pragma unroll
  for (int o = 0; o < ODIM; ++o) p[o] = 0.f;
  for (int it = 0; it < NDIM / 64; ++it) {
    int n = it * 64 + lane;
    float xv = xT[(size_t)b * NDIM + n];
    #pragma unroll
    for (int o = 0; o < ODIM; ++o) p[o] += xv * h2o_w[o * NDIM + n];
  }
  #pragma unroll
  for (int o = 0; o < ODIM; ++o) {
    float v = p[o];
    #pragma unroll
    for (int off = 32; off >= 1; off >>= 1) v += __shfl_down(v, off, 64);
    if (lane == 0) out[b * ODIM + o] = v + h2o_b[o];
  }
}

__global__ void horn_fail(float* out) {    // loud sentinel if ws too small
  int i = blockIdx.x * 256 + threadIdx.x;
  if (i < BATCH_N * ODIM) out[i] = 12345.0f;
}

extern "C" void kernel_launch(void* const* d_in, const int* in_sizes, int n_in,
                              void* d_out, int out_size, void* d_ws, size_t ws_size,
                              hipStream_t stream) {
  const float* batch = (const float*)d_in[0];
  const float* i2h_w = (const float*)d_in[1];
  const float* i2h_b = (const float*)d_in[2];
  const float* h2h_w = (const float*)d_in[3];
  const float* h2h_b = (const float*)d_in[4];
  const float* h2o_w = (const float*)d_in[5];
  const float* h2o_b = (const float*)d_in[6];
  float* out = (float*)d_out;
  char* ws = (char*)d_ws;

  if (ws_size < WS_NEED) {
    horn_fail<<<16, 256, 0, stream>>>(out);
    return;
  }

  (void)hipFuncSetAttribute(reinterpret_cast<const void*>(horn_persistent),
                            hipFuncAttributeMaxDynamicSharedMemorySize, 81920);

  hipMemsetAsync(ws + FLG_OFF, 0, FLG_BYTES, stream);    // flags = 0

  horn_convert<<<8192, 256, 0, stream>>>(batch, (unsigned short*)(ws + 0));

  horn_persistent<<<128, THREADS, 81920, stream>>>(
      (const unsigned short*)(ws + 0), i2h_w, i2h_b, h2h_w, h2h_b,
      (unsigned short*)(ws + YBUF_OFF), (unsigned int*)(ws + FLG_OFF),
      (float*)(ws + XT_OFF));

  horn_out<<<BATCH_N, 64, 0, stream>>>((const float*)(ws + XT_OFF), h2o_w, h2o_b, out);
}